// Round 7
// baseline (2423.013 us; speedup 1.0000x reference)
//
#include <hip/hip_runtime.h>

typedef unsigned short u16;
typedef unsigned int   u32;
typedef __attribute__((ext_vector_type(8))) short short8;
typedef __attribute__((ext_vector_type(4))) float f32x4;

#define DD      768
#define KK      6144   /* 8*768 : [root | W0..W6] concatenated on K */
#define NREL    7
#define NLAYERS 5
#define TILEB   196608 /* bytes per tile16 of native layout: 192*64*8*2 */

__device__ __forceinline__ float b2f(u16 v) {
  return __uint_as_float(((u32)v) << 16);
}
__device__ __forceinline__ u16 f2bf(float f) {
  u32 x = __float_as_uint(f);
  x += 0x7fffu + ((x >> 16) & 1u);
  return (u16)(x >> 16);
}

// ---------- setup kernels ----------

__global__ void cast_x_kernel(const float* __restrict__ x, u16* __restrict__ H, size_t n) {
  for (size_t i = ((size_t)blockIdx.x * 256 + threadIdx.x) * 4; i < n; i += (size_t)gridDim.x * 256 * 4) {
    float4 v = *(const float4*)&x[i];
    u32 lo = (u32)f2bf(v.x) | ((u32)f2bf(v.y) << 16);
    u32 hi = (u32)f2bf(v.z) | ((u32)f2bf(v.w) << 16);
    uint2 o; o.x = lo; o.y = hi;
    *(uint2*)&H[i] = o;
  }
}

__global__ void count_kernel(const int* __restrict__ eidx, const int* __restrict__ etype,
                             int* cnt_dst, int* cnt_rel, int E, int Nn) {
  int e = blockIdx.x * 256 + threadIdx.x;
  if (e >= E) return;
  int dst = eidx[E + e];
  int rel = etype[e] + 1;
  atomicAdd(&cnt_dst[dst], 1);
  atomicAdd(&cnt_rel[(size_t)rel * Nn + dst], 1);
}

__global__ __launch_bounds__(1024) void scan_kernel(const int* __restrict__ cnt, int* __restrict__ offs, int n) {
  __shared__ int part[1024];
  int t = threadIdx.x;
  int per = (n + 1023) / 1024;
  int base = t * per;
  int s = 0;
  for (int i = 0; i < per; ++i) { int idx = base + i; if (idx < n) s += cnt[idx]; }
  part[t] = s;
  __syncthreads();
  for (int o = 1; o < 1024; o <<= 1) {
    int v = (t >= o) ? part[t - o] : 0;
    __syncthreads();
    part[t] += v;
    __syncthreads();
  }
  int excl = (t == 0) ? 0 : part[t - 1];
  s = excl;
  for (int i = 0; i < per; ++i) { int idx = base + i; if (idx < n) { offs[idx] = s; s += cnt[idx]; } }
  if (t == 1023) offs[n] = part[1023];
}

__global__ void fillperm_kernel(const int* __restrict__ eidx, const int* __restrict__ offs,
                                int* fill, int* perm, int E) {
  int e = blockIdx.x * 256 + threadIdx.x;
  if (e >= E) return;
  int dst = eidx[E + e];
  int pos = offs[dst] + atomicAdd(&fill[dst], 1);
  perm[pos] = e;
}

// Per-layer weight conversion into MFMA-native fragment-major layout:
// Bn u16 index = ((n>>4)*192 + kabs>>5)*512 + (((kabs&31)>>3)*16 + (n&15))*8 + (kabs&7)
__global__ void wcat_kernel(const float* __restrict__ W, const float* __restrict__ R, u16* __restrict__ Bn) {
  __shared__ float t[32 * 33];
  int b = blockIdx.x;
  int s = b / 576, rem = b % 576;
  int kt = rem / 24, nt = rem % 24;
  const float* src = (s == 0) ? R : (W + (size_t)(s - 1) * DD * DD);
  int tj = threadIdx.x & 31, ti = threadIdx.x >> 5;  // ti 0..7
#pragma unroll
  for (int i = 0; i < 4; ++i) {
    int kk = kt * 32 + ti + i * 8;
    t[(ti + i * 8) * 33 + tj] = src[(size_t)kk * DD + nt * 32 + tj];
  }
  __syncthreads();
  int kkidx = s * 24 + kt;            // 32-wide K block index
  int kq = tj >> 3, e = tj & 7;
#pragma unroll
  for (int i = 0; i < 4; ++i) {
    int n = nt * 32 + ti + i * 8;
    size_t idx = ((size_t)(n >> 4) * 192 + kkidx) * 512 + (size_t)(kq * 16 + (n & 15)) * 8 + e;
    Bn[idx] = f2bf(t[tj * 33 + ti + i * 8]);
  }
}

// One block (192 thr) per destination node. rel is wave-uniform per edge ->
// per-thread register accumulation via 7-way switch; no LDS, no syncs.
// Writes all 8 segments (own row + 7 relation means) into A_native fragment layout.
__global__ __launch_bounds__(192) void aggregate_kernel(
    const u16* __restrict__ H, const int* __restrict__ esrc, const int* __restrict__ etype,
    const int* __restrict__ offs, const int* __restrict__ perm, const int* __restrict__ cnt_rel,
    u16* __restrict__ An, int node0, int Nn) {
  int v = node0 + blockIdx.x;
  int t = threadIdx.x;
  int j0 = t * 4;  // 192*4 = 768
  int rr = blockIdx.x;                 // chunk-local row
  int tile16 = rr >> 4, rsel = rr & 15;
  int kq = (j0 & 31) >> 3, e = j0 & 7, kk0 = j0 >> 5;
  // u16 index of this thread's 4-elem group in segment seg:
  // ((tile16*192 + seg*24 + kk0)*512 + (kq*16+rsel)*8 + e
  size_t base = ((size_t)tile16 * 192 + kk0) * 512 + (size_t)(kq * 16 + rsel) * 8 + e;

  // segment 0: own row
  *(uint2*)&An[base] = *(const uint2*)&H[(size_t)v * DD + j0];

  float a0[4] = {0,0,0,0}, a1[4] = {0,0,0,0}, a2[4] = {0,0,0,0}, a3[4] = {0,0,0,0};
  float a4[4] = {0,0,0,0}, a5[4] = {0,0,0,0}, a6[4] = {0,0,0,0};
  int beg = offs[v], end = offs[v + 1];
  for (int eI = beg; eI < end; ++eI) {
    int eid = perm[eI];
    int src = esrc[eid];
    int rel = etype[eid] + 1;
    uint2 w = *(const uint2*)&H[(size_t)src * DD + j0];
    float f0 = b2f((u16)(w.x & 0xffff));
    float f1 = b2f((u16)(w.x >> 16));
    float f2 = b2f((u16)(w.y & 0xffff));
    float f3 = b2f((u16)(w.y >> 16));
    switch (rel) {
      case 0: a0[0]+=f0; a0[1]+=f1; a0[2]+=f2; a0[3]+=f3; break;
      case 1: a1[0]+=f0; a1[1]+=f1; a1[2]+=f2; a1[3]+=f3; break;
      case 2: a2[0]+=f0; a2[1]+=f1; a2[2]+=f2; a2[3]+=f3; break;
      case 3: a3[0]+=f0; a3[1]+=f1; a3[2]+=f2; a3[3]+=f3; break;
      case 4: a4[0]+=f0; a4[1]+=f1; a4[2]+=f2; a4[3]+=f3; break;
      case 5: a5[0]+=f0; a5[1]+=f1; a5[2]+=f2; a5[3]+=f3; break;
      default: a6[0]+=f0; a6[1]+=f1; a6[2]+=f2; a6[3]+=f3; break;
    }
  }
  const float* regs[NREL] = {a0, a1, a2, a3, a4, a5, a6};
#pragma unroll
  for (int r = 0; r < NREL; ++r) {
    int c = cnt_rel[(size_t)r * Nn + v];
    float inv = (c > 0) ? 1.f / (float)c : 0.f;
    const float* a = regs[r];
    u32 lo = (u32)f2bf(a[0] * inv) | ((u32)f2bf(a[1] * inv) << 16);
    u32 hi = (u32)f2bf(a[2] * inv) | ((u32)f2bf(a[3] * inv) << 16);
    uint2 o; o.x = lo; o.y = hi;
    *(uint2*)&An[base + (size_t)(r + 1) * 24 * 512] = o;
  }
}

// ---------- flatmm GEMM: no LDS, no barriers. Operands pre-shuffled to
// fragment-major layout; K-loop = MFMA clusters <-> coalesced global loads
// into registers, double-buffered (AITER flatmm pattern, compiler-counted vmcnt).
// Per wave: 128x64 output; 4 waves/block share bm (A reuse via L1).

#define MFMA_(a_, b_, c_) __builtin_amdgcn_mfma_f32_16x16x32_bf16(a_, b_, c_, 0, 0, 0)

__global__ __launch_bounds__(256, 2) void gemmfl_kernel(
    const u16* __restrict__ An, const u16* __restrict__ Bn, const float* __restrict__ bias,
    u16* __restrict__ Hout, float* __restrict__ Cout, int Mvalid, int Mtiles) {
  int tid = threadIdx.x;
  int lane = tid & 63;
  int wv = tid >> 6;  // 0..3

  // XCD-bijective block swizzle (m204)
  int nwg = Mtiles * 3;
  int orig = (int)blockIdx.x;
  int q8 = nwg >> 3, r8 = nwg & 7;
  int xcd = orig & 7, rank = orig >> 3;
  int wg = (xcd < r8 ? xcd * (q8 + 1) : r8 * (q8 + 1) + (xcd - r8) * q8) + rank;
  int bm = wg / 3, bq = wg % 3;
  int nq = bq * 4 + wv;  // n-quarter 0..11 (64 cols each)

  const char* pa = (const char*)An + (size_t)(bm * 8) * TILEB;
  const char* pb = (const char*)Bn + (size_t)(nq * 4) * TILEB;
  int voff = lane * 16;

  f32x4 acc[8][4];
#pragma unroll
  for (int m = 0; m < 8; ++m)
#pragma unroll
    for (int n = 0; n < 4; ++n) acc[m][n] = (f32x4){0.f, 0.f, 0.f, 0.f};

#define LOADK(kk, ar, br)                                                 \
  do {                                                                    \
    int o_ = (kk) * 1024 + voff;                                          \
    _Pragma("unroll")                                                     \
    for (int m_ = 0; m_ < 8; ++m_) ar[m_] = *(const short8*)(pa + m_ * TILEB + o_); \
    _Pragma("unroll")                                                     \
    for (int n_ = 0; n_ < 4; ++n_) br[n_] = *(const short8*)(pb + n_ * TILEB + o_); \
  } while (0)

#define MF32(ar, br)                                                      \
  do {                                                                    \
    __builtin_amdgcn_s_setprio(1);                                        \
    _Pragma("unroll")                                                     \
    for (int m_ = 0; m_ < 8; ++m_)                                        \
      _Pragma("unroll")                                                   \
      for (int n_ = 0; n_ < 4; ++n_)                                      \
        acc[m_][n_] = MFMA_(ar[m_], br[n_], acc[m_][n_]);                 \
    __builtin_amdgcn_s_setprio(0);                                        \
  } while (0)

  short8 aA[8], bA[4], aB[8], bB[4];
  LOADK(0, aA, bA);
  LOADK(1, aB, bB);

  for (int kk = 0; kk < 188; kk += 2) {
    MF32(aA, bA);
    LOADK(kk + 2, aA, bA);
    MF32(aB, bB);
    LOADK(kk + 3, aB, bB);
  }
  MF32(aA, bA);
  LOADK(190, aA, bA);
  MF32(aB, bB);
  LOADK(191, aB, bB);
  MF32(aA, bA);
  MF32(aB, bB);

#undef LOADK
#undef MF32

  // ---- epilogue: bias + ReLU, write bf16 h_next / f32 out ----
  int rif = (lane >> 4) * 4;
  int cidx = lane & 15;
#pragma unroll
  for (int m = 0; m < 8; ++m) {
    int rl = bm * 128 + m * 16 + rif;
#pragma unroll
    for (int n = 0; n < 4; ++n) {
      int c = nq * 64 + n * 16 + cidx;
      float bv = bias[c];
#pragma unroll
      for (int j = 0; j < 4; ++j) {
        int r = rl + j;
        if (r < Mvalid) {
          float v = acc[m][n][j] + bv;
          v = v > 0.f ? v : 0.f;
          if (Hout) Hout[(size_t)r * DD + c] = f2bf(v);
          if (Cout) Cout[(size_t)r * DD + c] = v;
        }
      }
    }
  }
}

// ---------- host ----------

static inline size_t alignup(size_t x, size_t a) { return (x + a - 1) & ~(a - 1); }

extern "C" void kernel_launch(void* const* d_in, const int* in_sizes, int n_in,
                              void* d_out, int out_size, void* d_ws, size_t ws_size,
                              hipStream_t stream) {
  const float* x       = (const float*)d_in[0];
  const int*   eidx    = (const int*)d_in[1];
  const int*   etype   = (const int*)d_in[2];
  const float* weights = (const float*)d_in[3];
  const float* roots   = (const float*)d_in[4];
  const float* biases  = (const float*)d_in[5];
  float* out = (float*)d_out;

  const int Nn = in_sizes[0] / DD;  // 20000
  const int E  = in_sizes[2];       // 100000

  char* p = (char*)d_ws;
  size_t off = 0;
  auto carve = [&](size_t bytes) -> char* {
    char* r = p + off;
    off = alignup(off + bytes, 256);
    return r;
  };
  u16* H0      = (u16*)carve((size_t)Nn * DD * 2);
  u16* Bn      = (u16*)carve((size_t)DD * KK * 2);
  int* cnt_rel = (int*)carve((size_t)NREL * Nn * 4);
  int* cnt_dst = (int*)carve((size_t)Nn * 4);
  int* offs    = (int*)carve((size_t)(Nn + 1) * 4);
  int* fill    = (int*)carve((size_t)Nn * 4);
  int* perm    = (int*)carve((size_t)E * 4);

  size_t rem = (ws_size > off) ? (ws_size - off) : 0;
  int McCap = (int)(rem / ((size_t)KK * 2));
  int Mpad = ((Nn + 127) / 128) * 128;
  int Mc = (McCap < Mpad) ? (McCap & ~127) : Mpad;
  if (Mc < 128) return;  // workspace too small — fail visibly rather than corrupt
  u16* An = (u16*)(p + off);
  int nchunks = (Nn + Mc - 1) / Mc;
  u16* H1 = (u16*)d_out;  // bf16 ping buffer inside d_out (out_size*4 >= Nn*DD*2)

  (void)hipMemsetAsync(cnt_rel, 0, (size_t)NREL * Nn * 4, stream);
  (void)hipMemsetAsync(cnt_dst, 0, (size_t)Nn * 4, stream);
  (void)hipMemsetAsync(fill, 0, (size_t)Nn * 4, stream);

  int eg = (E + 255) / 256;
  count_kernel<<<eg, 256, 0, stream>>>(eidx, etype, cnt_dst, cnt_rel, E, Nn);
  scan_kernel<<<1, 1024, 0, stream>>>(cnt_dst, offs, Nn);
  fillperm_kernel<<<eg, 256, 0, stream>>>(eidx, offs, fill, perm, E);
  cast_x_kernel<<<2048, 256, 0, stream>>>(x, H0, (size_t)Nn * DD);

  const u16* Hin = H0;
  u16* Hnext = H1;
  for (int l = 0; l < NLAYERS; ++l) {
    wcat_kernel<<<8 * 576, 256, 0, stream>>>(weights + (size_t)l * NREL * DD * DD,
                                             roots + (size_t)l * DD * DD, Bn);
    for (int c = 0; c < nchunks; ++c) {
      int node0 = c * Mc;
      int nn = (Nn - node0 < Mc) ? (Nn - node0) : Mc;
      aggregate_kernel<<<nn, 192, 0, stream>>>(Hin, eidx, etype, offs, perm, cnt_rel,
                                               An, node0, Nn);
      int mt = (nn + 127) / 128;
      u16* ho = (l < NLAYERS - 1) ? (Hnext + (size_t)node0 * DD) : nullptr;
      float* co = (l == NLAYERS - 1) ? (out + (size_t)node0 * DD) : nullptr;
      gemmfl_kernel<<<mt * 3, 256, 0, stream>>>(An, Bn, biases + (size_t)l * DD, ho, co, nn, mt);
    }
    const u16* t_ = Hin;
    Hin = Hnext;
    Hnext = (u16*)t_;
  }
}

// Round 8
// 1430.244 us; speedup vs baseline: 1.6941x; 1.6941x over previous
//
#include <hip/hip_runtime.h>

typedef unsigned short u16;
typedef unsigned int   u32;
typedef __attribute__((ext_vector_type(8))) short short8;
typedef __attribute__((ext_vector_type(4))) float f32x4;

#define DD      768
#define KK      6144   /* 8*768 : [root | W0..W6] concatenated on K */
#define NREL    7
#define NLAYERS 5

__device__ __forceinline__ float b2f(u16 v) {
  return __uint_as_float(((u32)v) << 16);
}
__device__ __forceinline__ u16 f2bf(float f) {
  u32 x = __float_as_uint(f);
  x += 0x7fffu + ((x >> 16) & 1u);
  return (u16)(x >> 16);
}
__device__ __forceinline__ void gload16(const void* g, void* l) {
  __builtin_amdgcn_global_load_lds(
      (const __attribute__((address_space(1))) void*)g,
      (__attribute__((address_space(3))) void*)l, 16, 0, 0);
}

// ---------- setup kernels ----------

__global__ void cast_x_kernel(const float* __restrict__ x, u16* __restrict__ H, size_t n) {
  for (size_t i = ((size_t)blockIdx.x * 256 + threadIdx.x) * 4; i < n; i += (size_t)gridDim.x * 256 * 4) {
    float4 v = *(const float4*)&x[i];
    u32 lo = (u32)f2bf(v.x) | ((u32)f2bf(v.y) << 16);
    u32 hi = (u32)f2bf(v.z) | ((u32)f2bf(v.w) << 16);
    uint2 o; o.x = lo; o.y = hi;
    *(uint2*)&H[i] = o;
  }
}

__global__ void count_kernel(const int* __restrict__ eidx, const int* __restrict__ etype,
                             int* cnt_dst, int* cnt_rel, int E, int Nn) {
  int e = blockIdx.x * 256 + threadIdx.x;
  if (e >= E) return;
  int dst = eidx[E + e];
  int rel = etype[e] + 1;
  atomicAdd(&cnt_dst[dst], 1);
  atomicAdd(&cnt_rel[(size_t)rel * Nn + dst], 1);
}

__global__ __launch_bounds__(1024) void scan_kernel(const int* __restrict__ cnt, int* __restrict__ offs, int n) {
  __shared__ int part[1024];
  int t = threadIdx.x;
  int per = (n + 1023) / 1024;
  int base = t * per;
  int s = 0;
  for (int i = 0; i < per; ++i) { int idx = base + i; if (idx < n) s += cnt[idx]; }
  part[t] = s;
  __syncthreads();
  for (int o = 1; o < 1024; o <<= 1) {
    int v = (t >= o) ? part[t - o] : 0;
    __syncthreads();
    part[t] += v;
    __syncthreads();
  }
  int excl = (t == 0) ? 0 : part[t - 1];
  s = excl;
  for (int i = 0; i < per; ++i) { int idx = base + i; if (idx < n) { offs[idx] = s; s += cnt[idx]; } }
  if (t == 1023) offs[n] = part[1023];
}

__global__ void fillperm_kernel(const int* __restrict__ eidx, const int* __restrict__ offs,
                                int* fill, int* perm, int E) {
  int e = blockIdx.x * 256 + threadIdx.x;
  if (e >= E) return;
  int dst = eidx[E + e];
  int pos = offs[dst] + atomicAdd(&fill[dst], 1);
  perm[pos] = e;
}

// Per-layer weight conversion: Bt[n][seg*768+kk] = bf16( seg==0 ? roots[kk][n] : W[seg-1][kk][n] )
__global__ void wcat_kernel(const float* __restrict__ W, const float* __restrict__ R, u16* __restrict__ Bt) {
  __shared__ float t[32 * 33];
  int b = blockIdx.x;
  int s = b / 576, rem = b % 576;
  int kt = rem / 24, nt = rem % 24;
  const float* src = (s == 0) ? R : (W + (size_t)(s - 1) * DD * DD);
  int tj = threadIdx.x & 31, ti = threadIdx.x >> 5;  // ti 0..7
#pragma unroll
  for (int i = 0; i < 4; ++i) {
    int kk = kt * 32 + ti + i * 8;
    t[(ti + i * 8) * 33 + tj] = src[(size_t)kk * DD + nt * 32 + tj];
  }
  __syncthreads();
#pragma unroll
  for (int i = 0; i < 4; ++i) {
    int nn_ = nt * 32 + ti + i * 8;
    Bt[(size_t)nn_ * KK + (size_t)s * DD + kt * 32 + tj] = f2bf(t[tj * 33 + ti + i * 8]);
  }
}

// One block (192 thr) per destination node; per-thread register accumulation;
// fused own-row copy into segment 0.
__global__ __launch_bounds__(192) void aggregate_kernel(
    const u16* __restrict__ H, const int* __restrict__ esrc, const int* __restrict__ etype,
    const int* __restrict__ offs, const int* __restrict__ perm, const int* __restrict__ cnt_rel,
    u16* __restrict__ Acat, int node0, int Nn) {
  int v = node0 + blockIdx.x;
  int t = threadIdx.x;
  int j0 = t * 4;  // 192*4 = 768
  size_t rowbase = (size_t)blockIdx.x * KK;
  *(uint2*)&Acat[rowbase + j0] = *(const uint2*)&H[(size_t)v * DD + j0];
  float a0[4] = {0,0,0,0}, a1[4] = {0,0,0,0}, a2[4] = {0,0,0,0}, a3[4] = {0,0,0,0};
  float a4[4] = {0,0,0,0}, a5[4] = {0,0,0,0}, a6[4] = {0,0,0,0};
  int beg = offs[v], end = offs[v + 1];
  for (int e = beg; e < end; ++e) {
    int eid = perm[e];
    int src = esrc[eid];
    int rel = etype[eid] + 1;
    uint2 w = *(const uint2*)&H[(size_t)src * DD + j0];
    float f0 = b2f((u16)(w.x & 0xffff));
    float f1 = b2f((u16)(w.x >> 16));
    float f2 = b2f((u16)(w.y & 0xffff));
    float f3 = b2f((u16)(w.y >> 16));
    switch (rel) {
      case 0: a0[0]+=f0; a0[1]+=f1; a0[2]+=f2; a0[3]+=f3; break;
      case 1: a1[0]+=f0; a1[1]+=f1; a1[2]+=f2; a1[3]+=f3; break;
      case 2: a2[0]+=f0; a2[1]+=f1; a2[2]+=f2; a2[3]+=f3; break;
      case 3: a3[0]+=f0; a3[1]+=f1; a3[2]+=f2; a3[3]+=f3; break;
      case 4: a4[0]+=f0; a4[1]+=f1; a4[2]+=f2; a4[3]+=f3; break;
      case 5: a5[0]+=f0; a5[1]+=f1; a5[2]+=f2; a5[3]+=f3; break;
      default: a6[0]+=f0; a6[1]+=f1; a6[2]+=f2; a6[3]+=f3; break;
    }
  }
  const float* regs[NREL] = {a0, a1, a2, a3, a4, a5, a6};
#pragma unroll
  for (int r = 0; r < NREL; ++r) {
    int c = cnt_rel[(size_t)r * Nn + v];
    float inv = (c > 0) ? 1.f / (float)c : 0.f;
    const float* a = regs[r];
    u32 lo = (u32)f2bf(a[0] * inv) | ((u32)f2bf(a[1] * inv) << 16);
    u32 hi = (u32)f2bf(a[2] * inv) | ((u32)f2bf(a[3] * inv) << 16);
    uint2 o; o.x = lo; o.y = hi;
    *(uint2*)&Acat[rowbase + (size_t)(r + 1) * DD + j0] = o;
  }
}

// ---------- 256x256 8-wave GEMM: BK=64, 4-quadrant phases, HALF-TILE stage
// rotation with counted vmcnt(10) (never drains mid-loop) — m201/m218 discipline.
// A-h0 = a03 rows {0-63,128-191}, A-h1 = a47 rows; B-h0 = b01 rows, B-h1 = b23.
// Per tile t: P1 stages Bh1(t+1); P2 Ah0(t+2); P3 Bh0(t+2); P4 Ah1(t+2).
// vmcnt(10) at ends of P1,P2,P4; none at P3. Last two tiles peeled: [10,8,-,4],[2,0,-,-].

#define MFMA_(a_, b_, c_) __builtin_amdgcn_mfma_f32_16x16x32_bf16(a_, b_, c_, 0, 0, 0)
#define BAR   __builtin_amdgcn_s_barrier()
#define SB    __builtin_amdgcn_sched_barrier(0)
#define LGKM0 asm volatile("s_waitcnt lgkmcnt(0)" ::: "memory")
#define VM10  asm volatile("s_waitcnt vmcnt(10)" ::: "memory")
#define VM8   asm volatile("s_waitcnt vmcnt(8)" ::: "memory")
#define VM4   asm volatile("s_waitcnt vmcnt(4)" ::: "memory")
#define VM2   asm volatile("s_waitcnt vmcnt(2)" ::: "memory")
#define VM0   asm volatile("s_waitcnt vmcnt(0)" ::: "memory")

__global__ __launch_bounds__(512, 2) void gemm8p_kernel(
    const u16* __restrict__ A, const u16* __restrict__ Bt, const float* __restrict__ bias,
    u16* __restrict__ Hout, float* __restrict__ Cout, int Mvalid, int Mtiles) {
  // [slot][half][16KB]: A 64KB + B 64KB = 128KB
  __shared__ char smA[2][2][16384];
  __shared__ char smB[2][2][16384];

  int tid = threadIdx.x;
  int lane = tid & 63;
  int wv = tid >> 6;
  int wm = wv >> 2, wn = wv & 3;

  // XCD-bijective block swizzle (m204), bn fastest
  int nwg = Mtiles * 3;
  int orig = (int)blockIdx.x;
  int q8 = nwg >> 3, r8 = nwg & 7;
  int xcd = orig & 7, rank = orig >> 3;
  int wg = (xcd < r8 ? xcd * (q8 + 1) : r8 * (q8 + 1) + (xcd - r8) * q8) + rank;
  int bm = wg / 3, bn = wg % 3;

  // ---- stage source pointers [half][j]: linear LDS dest, inverse-swizzled source.
  // LDS pos q*16 (q=j*512+tid): row_l=q>>3, chunk=q&7; source chunk = chunk^(row_l&7).
  const char* pA[2][2];
  const char* pB[2][2];
#pragma unroll
  for (int j = 0; j < 2; ++j) {
    int q = j * 512 + tid, rl = q >> 3, gc = (q & 7) ^ (rl & 7);
    int ra0 = (rl & 63) + ((rl >> 6) << 7);   // A-h0 rows {0-63,128-191}
    int rb0 = (rl & 31) + ((rl >> 5) << 6);   // B-h0 rows {0-31,64-95,...}
    pA[0][j] = (const char*)A  + ((size_t)(bm * 256 + ra0) * KK) * 2 + gc * 16;
    pA[1][j] = pA[0][j] + (size_t)64 * KK * 2;
    pB[0][j] = (const char*)Bt + ((size_t)(bn * 256 + rb0) * KK) * 2 + gc * 16;
    pB[1][j] = pB[0][j] + (size_t)32 * KK * 2;
  }
  // swizzled ds_read lane offsets (k-slice 0 and 1 of BK=64)
  int rsel = lane & 15, kq = lane >> 4;
  int loff0 = rsel * 128 + (((kq)     ^ (rsel & 7)) * 16);
  int loff1 = rsel * 128 + (((kq + 4) ^ (rsel & 7)) * 16);

  f32x4 acc[8][4];
#pragma unroll
  for (int m = 0; m < 8; ++m)
#pragma unroll
    for (int n = 0; n < 4; ++n) acc[m][n] = (f32x4){0.f, 0.f, 0.f, 0.f};

  short8 a03[4][2], a47[4][2], b01[2][2], b23[2][2];

#define STGA(s_, h_, t2)                                                  \
  do {                                                                    \
    size_t ko_ = (size_t)(t2) * 128;                                      \
    gload16(pA[h_][0] + ko_, &smA[s_][h_][0] + tid * 16);                 \
    gload16(pA[h_][1] + ko_, &smA[s_][h_][8192] + tid * 16);              \
  } while (0)
#define STGB(s_, h_, t2)                                                  \
  do {                                                                    \
    size_t ko_ = (size_t)(t2) * 128;                                      \
    gload16(pB[h_][0] + ko_, &smB[s_][h_][0] + tid * 16);                 \
    gload16(pB[h_][1] + ko_, &smB[s_][h_][8192] + tid * 16);              \
  } while (0)

#define Q_(accm, accn, AR, BR)                                            \
  acc[accm][accn] = MFMA_(AR[0], BR[0], acc[accm][accn]);                 \
  acc[accm][accn] = MFMA_(AR[1], BR[1], acc[accm][accn]);

#define TILE(s_, S1, S2, S3, S4, V1, V2, V4)                              \
  do {                                                                    \
    /* P1/Q0: read a03+b01 (12); stage; MFMA a03 x b01 */                 \
    _Pragma("unroll")                                                     \
    for (int m = 0; m < 4; ++m) {                                         \
      a03[m][0] = *(const short8*)(&smA[s_][0][0] + (wm * 64 + m * 16) * 128 + loff0); \
      a03[m][1] = *(const short8*)(&smA[s_][0][0] + (wm * 64 + m * 16) * 128 + loff1); \
    }                                                                     \
    _Pragma("unroll")                                                     \
    for (int n = 0; n < 2; ++n) {                                         \
      b01[n][0] = *(const short8*)(&smB[s_][0][0] + (wn * 32 + n * 16) * 128 + loff0); \
      b01[n][1] = *(const short8*)(&smB[s_][0][0] + (wn * 32 + n * 16) * 128 + loff1); \
    }                                                                     \
    S1;                                                                   \
    asm volatile("s_waitcnt lgkmcnt(8)" ::: "memory");                    \
    BAR; LGKM0; SB;                                                       \
    __builtin_amdgcn_s_setprio(1);                                        \
    _Pragma("unroll")                                                     \
    for (int m = 0; m < 4; ++m) { Q_(m, 0, a03[m], b01[0]); Q_(m, 1, a03[m], b01[1]); } \
    __builtin_amdgcn_s_setprio(0);                                        \
    V1; BAR; SB;                                                          \
    /* P2/Q1: read a47 (8); stage; MFMA a47 x b01 */                      \
    _Pragma("unroll")                                                     \
    for (int m = 0; m < 4; ++m) {                                         \
      a47[m][0] = *(const short8*)(&smA[s_][1][0] + (wm * 64 + m * 16) * 128 + loff0); \
      a47[m][1] = *(const short8*)(&smA[s_][1][0] + (wm * 64 + m * 16) * 128 + loff1); \
    }                                                                     \
    S2;                                                                   \
    BAR; LGKM0; SB;                                                       \
    __builtin_amdgcn_s_setprio(1);                                        \
    _Pragma("unroll")                                                     \
    for (int m = 0; m < 4; ++m) { Q_(m + 4, 0, a47[m], b01[0]); Q_(m + 4, 1, a47[m], b01[1]); } \
    __builtin_amdgcn_s_setprio(0);                                        \
    V2; BAR; SB;                                                          \
    /* P3/Q2: read b23 (4); stage; MFMA a47 x b23 */                      \
    _Pragma("unroll")                                                     \
    for (int n = 0; n < 2; ++n) {                                         \
      b23[n][0] = *(const short8*)(&smB[s_][1][0] + (wn * 32 + n * 16) * 128 + loff0); \
      b23[n][1] = *(const short8*)(&smB[s_][1][0] + (wn * 32 + n * 16) * 128 + loff1); \
    }                                                                     \
    S3;                                                                   \
    BAR; LGKM0; SB;                                                       \
    __builtin_amdgcn_s_setprio(1);                                        \
    _Pragma("unroll")                                                     \
    for (int m = 0; m < 4; ++m) { Q_(m + 4, 2, a47[m], b23[0]); Q_(m + 4, 3, a47[m], b23[1]); } \
    __builtin_amdgcn_s_setprio(0);                                        \
    BAR; SB;                                                              \
    /* P4/Q3: no reads; stage; MFMA a03 x b23 */                          \
    S4;                                                                   \
    BAR; SB;                                                              \
    __builtin_amdgcn_s_setprio(1);                                        \
    _Pragma("unroll")                                                     \
    for (int m = 0; m < 4; ++m) { Q_(m, 2, a03[m], b23[0]); Q_(m, 3, a03[m], b23[1]); } \
    __builtin_amdgcn_s_setprio(0);                                        \
    V4; BAR; SB;                                                          \
  } while (0)

  // prologue: tiles 0,1 minus Bh1(1) = 7 half-tiles (14 loads); retire first 2 events.
  STGA(0, 0, 0); STGB(0, 0, 0); STGA(0, 1, 0); STGB(0, 1, 0);
  STGA(1, 0, 1); STGB(1, 0, 1); STGA(1, 1, 1);
  VM10; BAR; SB;

  for (int t = 0; t < 94; t += 2) {
    TILE(0, STGB(1, 1, t + 1), STGA(0, 0, t + 2), STGB(0, 0, t + 2), STGA(0, 1, t + 2), VM10, VM10, VM10);
    TILE(1, STGB(0, 1, t + 2), STGA(1, 0, t + 3), STGB(1, 0, t + 3), STGA(1, 1, t + 3), VM10, VM10, VM10);
  }
  // peeled tiles 94 (s=0) and 95 (s=1)
  TILE(0, STGB(1, 1, 95), , , , VM10, VM8, VM4);
  TILE(1, , , , , VM2, VM0, );

#undef TILE
#undef Q_
#undef STGA
#undef STGB

  // ---- epilogue: bias + ReLU, write bf16 h_next / f32 out ----
  int rif = (lane >> 4) * 4;
  int cidx = lane & 15;
#pragma unroll
  for (int m = 0; m < 8; ++m) {
    int rl = bm * 256 + wm * 128 + m * 16 + rif;
#pragma unroll
    for (int n = 0; n < 4; ++n) {
      int c = bn * 256 + wn * 64 + n * 16 + cidx;
      float bv = bias[c];
#pragma unroll
      for (int j = 0; j < 4; ++j) {
        int r = rl + j;
        if (r < Mvalid) {
          float v = acc[m][n][j] + bv;
          v = v > 0.f ? v : 0.f;
          if (Hout) Hout[(size_t)r * DD + c] = f2bf(v);
          if (Cout) Cout[(size_t)r * DD + c] = v;
        }
      }
    }
  }
}

// ---------- host ----------

static inline size_t alignup(size_t x, size_t a) { return (x + a - 1) & ~(a - 1); }

extern "C" void kernel_launch(void* const* d_in, const int* in_sizes, int n_in,
                              void* d_out, int out_size, void* d_ws, size_t ws_size,
                              hipStream_t stream) {
  const float* x       = (const float*)d_in[0];
  const int*   eidx    = (const int*)d_in[1];
  const int*   etype   = (const int*)d_in[2];
  const float* weights = (const float*)d_in[3];
  const float* roots   = (const float*)d_in[4];
  const float* biases  = (const float*)d_in[5];
  float* out = (float*)d_out;

  const int Nn = in_sizes[0] / DD;  // 20000
  const int E  = in_sizes[2];       // 100000

  char* p = (char*)d_ws;
  size_t off = 0;
  auto carve = [&](size_t bytes) -> char* {
    char* r = p + off;
    off = alignup(off + bytes, 256);
    return r;
  };
  u16* H0      = (u16*)carve((size_t)Nn * DD * 2);
  u16* Bt      = (u16*)carve((size_t)DD * KK * 2);
  int* cnt_rel = (int*)carve((size_t)NREL * Nn * 4);
  int* cnt_dst = (int*)carve((size_t)Nn * 4);
  int* offs    = (int*)carve((size_t)(Nn + 1) * 4);
  int* fill    = (int*)carve((size_t)Nn * 4);
  int* perm    = (int*)carve((size_t)E * 4);

  size_t rem = (ws_size > off) ? (ws_size - off) : 0;
  int McCap = (int)(rem / ((size_t)KK * 2));
  int Mpad = ((Nn + 255) / 256) * 256;
  int Mc = (McCap < Mpad) ? (McCap & ~255) : Mpad;
  if (Mc < 256) return;  // workspace too small — fail visibly rather than corrupt
  u16* Acat = (u16*)(p + off);
  int nchunks = (Nn + Mc - 1) / Mc;
  u16* H1 = (u16*)d_out;  // bf16 ping buffer inside d_out

  (void)hipMemsetAsync(cnt_rel, 0, (size_t)NREL * Nn * 4, stream);
  (void)hipMemsetAsync(cnt_dst, 0, (size_t)Nn * 4, stream);
  (void)hipMemsetAsync(fill, 0, (size_t)Nn * 4, stream);

  int eg = (E + 255) / 256;
  count_kernel<<<eg, 256, 0, stream>>>(eidx, etype, cnt_dst, cnt_rel, E, Nn);
  scan_kernel<<<1, 1024, 0, stream>>>(cnt_dst, offs, Nn);
  fillperm_kernel<<<eg, 256, 0, stream>>>(eidx, offs, fill, perm, E);
  cast_x_kernel<<<2048, 256, 0, stream>>>(x, H0, (size_t)Nn * DD);

  const u16* Hin = H0;
  u16* Hnext = H1;
  for (int l = 0; l < NLAYERS; ++l) {
    wcat_kernel<<<8 * 576, 256, 0, stream>>>(weights + (size_t)l * NREL * DD * DD,
                                             roots + (size_t)l * DD * DD, Bt);
    for (int c = 0; c < nchunks; ++c) {
      int node0 = c * Mc;
      int nn = (Nn - node0 < Mc) ? (Nn - node0) : Mc;
      aggregate_kernel<<<nn, 192, 0, stream>>>(Hin, eidx, etype, offs, perm, cnt_rel,
                                               Acat, node0, Nn);
      int mt = (nn + 255) / 256;
      u16* ho = (l < NLAYERS - 1) ? (Hnext + (size_t)node0 * DD) : nullptr;
      float* co = (l == NLAYERS - 1) ? (out + (size_t)node0 * DD) : nullptr;
      gemm8p_kernel<<<mt * 3, 512, 0, stream>>>(Acat, Bt, biases + (size_t)l * DD, ho, co, nn, mt);
    }
    const u16* t_ = Hin;
    Hin = Hnext;
    Hnext = (u16*)t_;
  }
}